// Round 9
// baseline (304.443 us; speedup 1.0000x reference)
//
#include <hip/hip_runtime.h>
#include <hip/hip_bf16.h>

typedef __attribute__((ext_vector_type(4)))  float f32x4;
typedef __attribute__((ext_vector_type(16))) float f32x16;
typedef __attribute__((ext_vector_type(8)))  short bf16x8;

#define LOG2E 1.44269504088896340736f

// native v_exp_f32 (1 instr, ~1 ulp); plain exp2f lowers to precise OCML (~30 cyc).
#if __has_builtin(__builtin_amdgcn_exp2f)
static __device__ __forceinline__ float exp2_native(float x) {
  return __builtin_amdgcn_exp2f(x);
}
#else
extern "C" __device__ float __ocml_native_exp2_f32(float);
static __device__ __forceinline__ float exp2_native(float x) {
  return __ocml_native_exp2_f32(x);
}
#endif

// bf16 truncation pack: low ushort <- a, high ushort <- b (1x v_perm_b32).
static __device__ __forceinline__ unsigned int pack_trunc_f(float a, float b) {
  return __builtin_amdgcn_perm(__float_as_uint(b), __float_as_uint(a), 0x07060302);
}

// async global->LDS, 16B/lane: LDS dest = wave-uniform base + lane*16 (HW adds)
typedef const __attribute__((address_space(1))) unsigned int gu32;
typedef __attribute__((address_space(3))) unsigned int lu32;
static __device__ __forceinline__ void gload_lds16(const void* g, void* l) {
  __builtin_amdgcn_global_load_lds((gu32*)g, (lu32*)l, 16, 0, 0);
}

// ---------------------------------------------------------------------------
// proj: y = x(32768x64) * K^T(64x80) via MFMA 16x16x32. Block=256thr/4 waves.
// g pre-scaled by log2(e) so attn uses native exp2.
// h stored per 128-key tile as [b][kt(32)][c(64)][136 slots] bf16 (8-slot row
// pad; stride 136 gave 0 measured conflicts R4-R8), tile stride 17408 B.
// Key position within tile = bitswap2<->3(key&127): attn's S^T C-layout ==
// PV A-layout with contiguous B-frags.
// ---------------------------------------------------------------------------
__global__ __launch_bounds__(256) void proj_kernel(
    const float* __restrict__ x, const float* __restrict__ kf,
    const float* __restrict__ kg, const float* __restrict__ kh,
    unsigned short* __restrict__ f_b, unsigned short* __restrict__ g_b,
    unsigned short* __restrict__ h_p)
{
  __shared__ unsigned short Kt[80*72];
  const int t = threadIdx.x, blk = blockIdx.x;

  #pragma unroll
  for (int r = 0; r < 20; ++r) {
    int idx = r*256 + t;                 // 5120 = 80x64
    int o = idx >> 6, c = idx & 63;
    float v = (o < 8) ? kf[c*8 + o]
            : (o < 16) ? kg[c*8 + (o-8)] * LOG2E
            : kh[c*64 + (o-16)];
    Kt[o*72 + c] = (unsigned short)(__float_as_uint(v) >> 16);
  }
  __syncthreads();

  const int w = t >> 6, lane = t & 63, l15 = lane & 15, quad = lane >> 4;
  const int Rbase = blk*64 + w*16;
  const int R = Rbase + l15;

  bf16x8 af[2];
  #pragma unroll
  for (int kk = 0; kk < 2; ++kk) {
    const float* xp = x + (long)R*64 + kk*32 + quad*8;
    float4 v0 = *(const float4*)xp;
    float4 v1 = *(const float4*)(xp + 4);
    union { unsigned int u[4]; bf16x8 v; } p;
    p.u[0] = pack_trunc_f(v0.x, v0.y);
    p.u[1] = pack_trunc_f(v0.z, v0.w);
    p.u[2] = pack_trunc_f(v1.x, v1.y);
    p.u[3] = pack_trunc_f(v1.z, v1.w);
    af[kk] = p.v;
  }

  f32x4 acc[5];
  #pragma unroll
  for (int nt = 0; nt < 5; ++nt) { f32x4 z = {}; acc[nt] = z; }

  #pragma unroll
  for (int nt = 0; nt < 5; ++nt)
    #pragma unroll
    for (int kk = 0; kk < 2; ++kk) {
      bf16x8 bfv = *(const bf16x8*)&Kt[(nt*16 + l15)*72 + kk*32 + quad*8];
      acc[nt] = __builtin_amdgcn_mfma_f32_16x16x32_bf16(af[kk], bfv, acc[nt], 0, 0, 0);
    }

  const int bt = Rbase >> 12;            // batch
  const int kt = (Rbase >> 7) & 31;      // 128-key tile index
  const int base = ((blk & 1) << 6) + (w << 4);   // key&127 base for C rows
  // permuted store position: swap bits 2<->3 of (base + 4*quad + rr)
  const int pi = base + ((quad & 1) << 3) + (((quad >> 1) & 1) << 2);

  #pragma unroll
  for (int rr = 0; rr < 4; ++rr) {
    const int nq = (Rbase + quad*4 + rr) & 4095;
    unsigned short v = (unsigned short)(__float_as_uint(acc[0][rr]) >> 16);
    if (l15 < 8) f_b[((long)bt*4096 + nq)*8 + l15] = v;
    else         g_b[((long)bt*4096 + nq)*8 + (l15 - 8)] = v;
  }
  #pragma unroll
  for (int nt = 1; nt < 5; ++nt) {
    const int c = (nt - 1)*16 + l15;
    uint2 v;
    v.x = pack_trunc_f(acc[nt][0], acc[nt][1]);
    v.y = pack_trunc_f(acc[nt][2], acc[nt][3]);
    *(uint2*)(h_p + ((long)(bt*32 + kt)*64 + c)*136 + pi) = v;
  }
}

// ---------------------------------------------------------------------------
// attn: split-K flash attention (no-max softmax; |s| << 1 by construction).
// Grid (16 qtiles, 8 batch, 8 splits) = 1024 blocks; block = 256 thr = 4
// waves sharing one buffer pair; wave = 64 queries (2 q-groups sharing every
// LDS read).  128-key double-buffered tiles, blob/buf = [h 17408][f 2048] =
// 19456 B; x2 = 38912 B -> 4 blocks/CU = 4 waves/SIMD (launch_bounds(256,4),
// VGPR cap 128 > 84 measured R8 -> no spill).
// R8 post-mortem: 64-key tiles at same occupancy ran SLOWER than R6's
// 128-key tiles at half occupancy -- barrier-phase overhead dominates; this
// round has both the fat phases (16/CU, ~1900 issue-cyc each) and the waves.
// ONE barrier per tile: barrier (drains tile-t loads) -> issue t+1 into the
// other buffer -> compute t.
// ---------------------------------------------------------------------------
__global__ __launch_bounds__(256, 4) void attn_kernel(
    const unsigned short* __restrict__ f_b, const unsigned short* __restrict__ g_b,
    const unsigned short* __restrict__ h_p, unsigned short* __restrict__ po,
    float* __restrict__ pl)
{
  __shared__ char bufs[2][19456];   // [h 17408][f 2048]

  const int t = threadIdx.x;
  const int w = t >> 6, lane = t & 63, l31 = lane & 31, a = lane >> 5;
  const int qb = blockIdx.x, b = blockIdx.y, sp = blockIdx.z;
  const int q0w = qb*256 + w*64;

  // g B-frags, one per q-group: n = q = l31, k = a*8+j ; real only at a=0
  bf16x8 gf[2];
  #pragma unroll
  for (int qg = 0; qg < 2; ++qg) {
    bf16x8 gv = *(const bf16x8*)(g_b + ((long)b*4096 + q0w + qg*32 + l31)*8);
    bf16x8 z = {};
    gf[qg] = (a == 0) ? gv : z;
  }

  f32x16 oacc[2][2];
  { f32x16 z = {}; oacc[0][0] = z; oacc[0][1] = z; oacc[1][0] = z; oacc[1][1] = z; }
  float l_run[2] = {0.f, 0.f};

  const char* hp_b = (const char*)h_p + (long)b*32*17408;
  const char* fb_b = (const char*)f_b + (long)b*65536;

  // stage 128-key tile kt into bufs[bi]: 19 x 1024B wave-uniform rounds,
  // round r = 4i + w (waves 0-2: 5 rounds, wave 3: 4). r<17 -> h, else f.
  auto stage = [&](int bi, int kt) {
    const char* hsrc = hp_b + (long)kt*17408;
    const char* fsrc = fb_b + (long)kt*2048;
    char* dst = &bufs[bi][0];
    #pragma unroll
    for (int i = 0; i < 4; ++i) {
      const int r = 4*i + w;                       // 0..15: always h
      gload_lds16(hsrc + r*1024 + lane*16, dst + r*1024);
    }
    if (w == 0)      gload_lds16(hsrc + 16*1024 + lane*16, dst + 16*1024);
    else if (w < 3)  gload_lds16(fsrc + (w-1)*1024 + lane*16, dst + (16+w)*1024);
  };

  stage(0, sp*4);

  for (int ktl = 0; ktl < 4; ++ktl) {
    __syncthreads();                   // drains tile-ktl loads; protects reuse
    if (ktl < 3) stage((ktl + 1) & 1, sp*4 + ktl + 1);

    const unsigned short* hts = (const unsigned short*)&bufs[ktl & 1][0];
    const unsigned short* fts = (const unsigned short*)&bufs[ktl & 1][17408];

    #pragma unroll
    for (int mt = 0; mt < 4; ++mt) {
      // S^T sub-tile: 32 keys (storage order) x 64 queries (2 groups)
      bf16x8 afv = *(const bf16x8*)&fts[(mt*32 + l31)*8];
      f32x16 zz = {};
      f32x16 sc0 = __builtin_amdgcn_mfma_f32_32x32x16_bf16(afv, gf[0], zz, 0, 0, 0);
      f32x16 sc1 = __builtin_amdgcn_mfma_f32_32x32x16_bf16(afv, gf[1], zz, 0, 0, 0);

      // exp + row-sum + IMMEDIATE pack: sc0/sc1 dead before any PV MFMA
      unsigned int ap[2][2][4];        // [qg][half][slot]
      float la0 = 0.f, lb0 = 0.f, la1 = 0.f, lb1 = 0.f;
      #pragma unroll
      for (int r = 0; r < 16; r += 2) {
        sc0[r]   = exp2_native(sc0[r]);
        sc0[r+1] = exp2_native(sc0[r+1]);
        sc1[r]   = exp2_native(sc1[r]);
        sc1[r+1] = exp2_native(sc1[r+1]);
        la0 += sc0[r]; lb0 += sc0[r+1];
        la1 += sc1[r]; lb1 += sc1[r+1];
        ap[0][r >> 3][(r & 7) >> 1] = pack_trunc_f(sc0[r], sc0[r+1]);
        ap[1][r >> 3][(r & 7) >> 1] = pack_trunc_f(sc1[r], sc1[r+1]);
      }
      l_run[0] += la0 + lb0;
      l_run[1] += la1 + lb1;

      #pragma unroll
      for (int half = 0; half < 2; ++half) {
        const int s = mt*2 + half;     // PV K-step: contraction k in [16s,16s+16)
        bf16x8 bh0 = *(const bf16x8*)&hts[(l31)*136      + s*16 + a*8];
        bf16x8 bh1 = *(const bf16x8*)&hts[(32 + l31)*136 + s*16 + a*8];
        bf16x8 a0 = *(const bf16x8*)&ap[0][half][0];
        bf16x8 a1 = *(const bf16x8*)&ap[1][half][0];
        oacc[0][0] = __builtin_amdgcn_mfma_f32_32x32x16_bf16(a0, bh0, oacc[0][0], 0, 0, 0);
        oacc[0][1] = __builtin_amdgcn_mfma_f32_32x32x16_bf16(a0, bh1, oacc[0][1], 0, 0, 0);
        oacc[1][0] = __builtin_amdgcn_mfma_f32_32x32x16_bf16(a1, bh0, oacc[1][0], 0, 0, 0);
        oacc[1][1] = __builtin_amdgcn_mfma_f32_32x32x16_bf16(a1, bh1, oacc[1][1], 0, 0, 0);
      }
    }
  }

  const long sb = (long)sp*8 + b;
  #pragma unroll
  for (int qg = 0; qg < 2; ++qg) {
    float l = l_run[qg] + __shfl_xor(l_run[qg], 32);
    if (lane < 32) pl[(sb << 12) + q0w + qg*32 + l31] = l;
    // partial o: C col = c = nt*32+l31, row q = (r&3)+8*(r>>2)+4a
    unsigned short* pob = po + ((sb << 12) + q0w + qg*32)*64;
    #pragma unroll
    for (int nt = 0; nt < 2; ++nt)
      #pragma unroll
      for (int r = 0; r < 16; ++r) {
        const int q = (r & 3) + 8*(r >> 2) + 4*a;
        pob[(long)q*64 + nt*32 + l31] =
            (unsigned short)(__float_as_uint(oacc[qg][nt][r]) >> 16);
      }
  }
}

// ---------------------------------------------------------------------------
// combine: out = gamma * (sum_s po) / (sum_s pl) + x.  One thread = 8 channels.
// ---------------------------------------------------------------------------
__global__ __launch_bounds__(256) void combine_kernel(
    const float* __restrict__ x, const unsigned short* __restrict__ po,
    const float* __restrict__ pl, const float* __restrict__ gamma_p,
    float* __restrict__ out)
{
  const long tid = (long)blockIdx.x*256 + threadIdx.x;   // 262144
  const long bn = tid >> 3;
  const int c0 = (int)(tid & 7)*8;

  float l = 0.f;
  float o[8];
  #pragma unroll
  for (int i = 0; i < 8; ++i) o[i] = 0.f;
  #pragma unroll
  for (int s = 0; s < 8; ++s) {
    l += pl[(long)s*32768 + bn];
    uint4 v = *(const uint4*)(po + ((long)s*32768 + bn)*64 + c0);
    const unsigned short* pv = (const unsigned short*)&v;
    #pragma unroll
    for (int i = 0; i < 8; ++i)
      o[i] += __uint_as_float((unsigned int)pv[i] << 16);
  }
  const float scale = gamma_p[0] / l;
  const float* xp = x + bn*64 + c0;
  float4 x0 = *(const float4*)xp;
  float4 x1 = *(const float4*)(xp + 4);
  float4 r0, r1;
  r0.x = fmaf(scale, o[0], x0.x);
  r0.y = fmaf(scale, o[1], x0.y);
  r0.z = fmaf(scale, o[2], x0.z);
  r0.w = fmaf(scale, o[3], x0.w);
  r1.x = fmaf(scale, o[4], x1.x);
  r1.y = fmaf(scale, o[5], x1.y);
  r1.z = fmaf(scale, o[6], x1.z);
  r1.w = fmaf(scale, o[7], x1.w);
  float* op = out + bn*64 + c0;
  *(float4*)op = r0;
  *(float4*)(op + 4) = r1;
}

extern "C" void kernel_launch(void* const* d_in, const int* in_sizes, int n_in,
                              void* d_out, int out_size, void* d_ws, size_t ws_size,
                              hipStream_t stream) {
  const float* x  = (const float*)d_in[0];
  const float* kf = (const float*)d_in[1];
  const float* kg = (const float*)d_in[2];
  const float* kh = (const float*)d_in[3];
  const float* gamma = (const float*)d_in[4];
  float* out = (float*)d_out;

  char* ws = (char*)d_ws;
  unsigned short* h_p = (unsigned short*)ws;                  // 8*32*8704*2 = 4,456,448
  unsigned short* f_b = (unsigned short*)(ws + 4456448);      // 524,288
  unsigned short* g_b = (unsigned short*)(ws + 4980736);      // 524,288
  unsigned short* po  = (unsigned short*)(ws + 5505024);      // 8*8*4096*64*2 = 33,554,432
  float*          pl  = (float*)(ws + 39059456);              // 8*8*4096*4 = 1,048,576

  proj_kernel<<<512, 256, 0, stream>>>(x, kf, kg, kh, f_b, g_b, h_p);
  attn_kernel<<<dim3(16, 8, 8), 256, 0, stream>>>(f_b, g_b, h_p, po, pl);
  combine_kernel<<<1024, 256, 0, stream>>>(x, po, pl, gamma, out);
}

// Round 10
// 252.247 us; speedup vs baseline: 1.2069x; 1.2069x over previous
//
#include <hip/hip_runtime.h>
#include <hip/hip_bf16.h>

typedef __attribute__((ext_vector_type(4)))  float f32x4;
typedef __attribute__((ext_vector_type(16))) float f32x16;
typedef __attribute__((ext_vector_type(8)))  short bf16x8;

#define LOG2E 1.44269504088896340736f

// native v_exp_f32 (1 instr, ~1 ulp); plain exp2f lowers to precise OCML (~30 cyc).
#if __has_builtin(__builtin_amdgcn_exp2f)
static __device__ __forceinline__ float exp2_native(float x) {
  return __builtin_amdgcn_exp2f(x);
}
#else
extern "C" __device__ float __ocml_native_exp2_f32(float);
static __device__ __forceinline__ float exp2_native(float x) {
  return __ocml_native_exp2_f32(x);
}
#endif

// bf16 truncation pack: low ushort <- a, high ushort <- b (1x v_perm_b32).
static __device__ __forceinline__ unsigned int pack_trunc_f(float a, float b) {
  return __builtin_amdgcn_perm(__float_as_uint(b), __float_as_uint(a), 0x07060302);
}

// async global->LDS, 16B/lane: LDS dest = wave-uniform base + lane*16 (HW adds)
typedef const __attribute__((address_space(1))) unsigned int gu32;
typedef __attribute__((address_space(3))) unsigned int lu32;
static __device__ __forceinline__ void gload_lds16(const void* g, void* l) {
  __builtin_amdgcn_global_load_lds((gu32*)g, (lu32*)l, 16, 0, 0);
}

// ---------------------------------------------------------------------------
// proj: y = x(32768x64) * K^T(64x80) via MFMA 16x16x32. Block=256thr/4 waves.
// g pre-scaled by log2(e) so attn uses native exp2.
// h stored per 128-key tile as [b][kt(32)][c(64)][136 slots] bf16 (8-slot row
// pad; stride 136 gave 0 measured conflicts R4-R9), tile stride 17408 B.
// Key position within tile = bitswap2<->3(key&127): attn's S^T C-layout ==
// PV A-layout with contiguous B-frags.
// ---------------------------------------------------------------------------
__global__ __launch_bounds__(256) void proj_kernel(
    const float* __restrict__ x, const float* __restrict__ kf,
    const float* __restrict__ kg, const float* __restrict__ kh,
    unsigned short* __restrict__ f_b, unsigned short* __restrict__ g_b,
    unsigned short* __restrict__ h_p)
{
  __shared__ unsigned short Kt[80*72];
  const int t = threadIdx.x, blk = blockIdx.x;

  #pragma unroll
  for (int r = 0; r < 20; ++r) {
    int idx = r*256 + t;                 // 5120 = 80x64
    int o = idx >> 6, c = idx & 63;
    float v = (o < 8) ? kf[c*8 + o]
            : (o < 16) ? kg[c*8 + (o-8)] * LOG2E
            : kh[c*64 + (o-16)];
    Kt[o*72 + c] = (unsigned short)(__float_as_uint(v) >> 16);
  }
  __syncthreads();

  const int w = t >> 6, lane = t & 63, l15 = lane & 15, quad = lane >> 4;
  const int Rbase = blk*64 + w*16;
  const int R = Rbase + l15;

  bf16x8 af[2];
  #pragma unroll
  for (int kk = 0; kk < 2; ++kk) {
    const float* xp = x + (long)R*64 + kk*32 + quad*8;
    float4 v0 = *(const float4*)xp;
    float4 v1 = *(const float4*)(xp + 4);
    union { unsigned int u[4]; bf16x8 v; } p;
    p.u[0] = pack_trunc_f(v0.x, v0.y);
    p.u[1] = pack_trunc_f(v0.z, v0.w);
    p.u[2] = pack_trunc_f(v1.x, v1.y);
    p.u[3] = pack_trunc_f(v1.z, v1.w);
    af[kk] = p.v;
  }

  f32x4 acc[5];
  #pragma unroll
  for (int nt = 0; nt < 5; ++nt) { f32x4 z = {}; acc[nt] = z; }

  #pragma unroll
  for (int nt = 0; nt < 5; ++nt)
    #pragma unroll
    for (int kk = 0; kk < 2; ++kk) {
      bf16x8 bfv = *(const bf16x8*)&Kt[(nt*16 + l15)*72 + kk*32 + quad*8];
      acc[nt] = __builtin_amdgcn_mfma_f32_16x16x32_bf16(af[kk], bfv, acc[nt], 0, 0, 0);
    }

  const int bt = Rbase >> 12;            // batch
  const int kt = (Rbase >> 7) & 31;      // 128-key tile index
  const int base = ((blk & 1) << 6) + (w << 4);   // key&127 base for C rows
  // permuted store position: swap bits 2<->3 of (base + 4*quad + rr)
  const int pi = base + ((quad & 1) << 3) + (((quad >> 1) & 1) << 2);

  #pragma unroll
  for (int rr = 0; rr < 4; ++rr) {
    const int nq = (Rbase + quad*4 + rr) & 4095;
    unsigned short v = (unsigned short)(__float_as_uint(acc[0][rr]) >> 16);
    if (l15 < 8) f_b[((long)bt*4096 + nq)*8 + l15] = v;
    else         g_b[((long)bt*4096 + nq)*8 + (l15 - 8)] = v;
  }
  #pragma unroll
  for (int nt = 1; nt < 5; ++nt) {
    const int c = (nt - 1)*16 + l15;
    uint2 v;
    v.x = pack_trunc_f(acc[nt][0], acc[nt][1]);
    v.y = pack_trunc_f(acc[nt][2], acc[nt][3]);
    *(uint2*)(h_p + ((long)(bt*32 + kt)*64 + c)*136 + pi) = v;
  }
}

// ---------------------------------------------------------------------------
// attn: split-K flash attention (no-max softmax; |s| << 1 by construction).
// Grid (16 qtiles, 8 batch, 8 splits) = 1024 blocks; block = 256 thr = 4
// waves sharing one buffer pair; wave = 64 queries (2 q-groups sharing every
// LDS read).  128-key double-buffered tiles, blob/buf = [h 17408][f 2048] =
// 19456 B; x2 = 38912 B.
//
// REGISTER LAW (R7/R8/R9 post-mortems): true footprint = ~84 arch VGPRs
// + 64 acc (oacc) = ~148 unified regs; AGPRs don't show in VGPR_Count but
// count against the per-wave cap. launch_bounds min-waves/EU=4 (cap 128)
// ALWAYS spills this kernel (R7: 0.67 GB, R9: 0.6 GB scratch traffic).
// (256,3) -> cap ~170: no spill; 3 blocks/CU (LDS 117 KB), 3 waves/EU,
// 16 fat barrier-phases per CU (R8's 64 thin phases were the regression).
// ONE barrier per tile: barrier (drains tile-t loads) -> issue t+1 into the
// other buffer -> compute t.
// ---------------------------------------------------------------------------
__global__ __launch_bounds__(256, 3) void attn_kernel(
    const unsigned short* __restrict__ f_b, const unsigned short* __restrict__ g_b,
    const unsigned short* __restrict__ h_p, unsigned short* __restrict__ po,
    float* __restrict__ pl)
{
  __shared__ char bufs[2][19456];   // [h 17408][f 2048]

  const int t = threadIdx.x;
  const int w = t >> 6, lane = t & 63, l31 = lane & 31, a = lane >> 5;
  const int qb = blockIdx.x, b = blockIdx.y, sp = blockIdx.z;
  const int q0w = qb*256 + w*64;

  // g B-frags, one per q-group: n = q = l31, k = a*8+j ; real only at a=0
  bf16x8 gf[2];
  #pragma unroll
  for (int qg = 0; qg < 2; ++qg) {
    bf16x8 gv = *(const bf16x8*)(g_b + ((long)b*4096 + q0w + qg*32 + l31)*8);
    bf16x8 z = {};
    gf[qg] = (a == 0) ? gv : z;
  }

  f32x16 oacc[2][2];
  { f32x16 z = {}; oacc[0][0] = z; oacc[0][1] = z; oacc[1][0] = z; oacc[1][1] = z; }
  float l_run[2] = {0.f, 0.f};

  const char* hp_b = (const char*)h_p + (long)b*32*17408;
  const char* fb_b = (const char*)f_b + (long)b*65536;

  // stage 128-key tile kt into bufs[bi]: 19 x 1024B wave-uniform rounds,
  // round r = 4i + w (waves 0-2: 5 rounds, wave 3: 4). r<17 -> h, else f.
  auto stage = [&](int bi, int kt) {
    const char* hsrc = hp_b + (long)kt*17408;
    const char* fsrc = fb_b + (long)kt*2048;
    char* dst = &bufs[bi][0];
    #pragma unroll
    for (int i = 0; i < 4; ++i) {
      const int r = 4*i + w;                       // 0..15: always h
      gload_lds16(hsrc + r*1024 + lane*16, dst + r*1024);
    }
    if (w == 0)      gload_lds16(hsrc + 16*1024 + lane*16, dst + 16*1024);
    else if (w < 3)  gload_lds16(fsrc + (w-1)*1024 + lane*16, dst + (16+w)*1024);
  };

  stage(0, sp*4);

  for (int ktl = 0; ktl < 4; ++ktl) {
    __syncthreads();                   // drains tile-ktl loads; protects reuse
    if (ktl < 3) stage((ktl + 1) & 1, sp*4 + ktl + 1);

    const unsigned short* hts = (const unsigned short*)&bufs[ktl & 1][0];
    const unsigned short* fts = (const unsigned short*)&bufs[ktl & 1][17408];

    #pragma unroll
    for (int mt = 0; mt < 4; ++mt) {
      // S^T sub-tile: 32 keys (storage order) x 64 queries (2 groups)
      bf16x8 afv = *(const bf16x8*)&fts[(mt*32 + l31)*8];
      f32x16 zz = {};
      f32x16 sc0 = __builtin_amdgcn_mfma_f32_32x32x16_bf16(afv, gf[0], zz, 0, 0, 0);
      f32x16 sc1 = __builtin_amdgcn_mfma_f32_32x32x16_bf16(afv, gf[1], zz, 0, 0, 0);

      // exp + row-sum + IMMEDIATE pack: sc0/sc1 dead before any PV MFMA
      unsigned int ap[2][2][4];        // [qg][half][slot]
      float la0 = 0.f, lb0 = 0.f, la1 = 0.f, lb1 = 0.f;
      #pragma unroll
      for (int r = 0; r < 16; r += 2) {
        sc0[r]   = exp2_native(sc0[r]);
        sc0[r+1] = exp2_native(sc0[r+1]);
        sc1[r]   = exp2_native(sc1[r]);
        sc1[r+1] = exp2_native(sc1[r+1]);
        la0 += sc0[r]; lb0 += sc0[r+1];
        la1 += sc1[r]; lb1 += sc1[r+1];
        ap[0][r >> 3][(r & 7) >> 1] = pack_trunc_f(sc0[r], sc0[r+1]);
        ap[1][r >> 3][(r & 7) >> 1] = pack_trunc_f(sc1[r], sc1[r+1]);
      }
      l_run[0] += la0 + lb0;
      l_run[1] += la1 + lb1;

      #pragma unroll
      for (int half = 0; half < 2; ++half) {
        const int s = mt*2 + half;     // PV K-step: contraction k in [16s,16s+16)
        bf16x8 bh0 = *(const bf16x8*)&hts[(l31)*136      + s*16 + a*8];
        bf16x8 bh1 = *(const bf16x8*)&hts[(32 + l31)*136 + s*16 + a*8];
        bf16x8 a0 = *(const bf16x8*)&ap[0][half][0];
        bf16x8 a1 = *(const bf16x8*)&ap[1][half][0];
        oacc[0][0] = __builtin_amdgcn_mfma_f32_32x32x16_bf16(a0, bh0, oacc[0][0], 0, 0, 0);
        oacc[0][1] = __builtin_amdgcn_mfma_f32_32x32x16_bf16(a0, bh1, oacc[0][1], 0, 0, 0);
        oacc[1][0] = __builtin_amdgcn_mfma_f32_32x32x16_bf16(a1, bh0, oacc[1][0], 0, 0, 0);
        oacc[1][1] = __builtin_amdgcn_mfma_f32_32x32x16_bf16(a1, bh1, oacc[1][1], 0, 0, 0);
      }
    }
  }

  const long sb = (long)sp*8 + b;
  #pragma unroll
  for (int qg = 0; qg < 2; ++qg) {
    float l = l_run[qg] + __shfl_xor(l_run[qg], 32);
    if (lane < 32) pl[(sb << 12) + q0w + qg*32 + l31] = l;
    // partial o: C col = c = nt*32+l31, row q = (r&3)+8*(r>>2)+4a
    unsigned short* pob = po + ((sb << 12) + q0w + qg*32)*64;
    #pragma unroll
    for (int nt = 0; nt < 2; ++nt)
      #pragma unroll
      for (int r = 0; r < 16; ++r) {
        const int q = (r & 3) + 8*(r >> 2) + 4*a;
        pob[(long)q*64 + nt*32 + l31] =
            (unsigned short)(__float_as_uint(oacc[qg][nt][r]) >> 16);
      }
  }
}

// ---------------------------------------------------------------------------
// combine: out = gamma * (sum_s po) / (sum_s pl) + x.  One thread = 8 channels.
// ---------------------------------------------------------------------------
__global__ __launch_bounds__(256) void combine_kernel(
    const float* __restrict__ x, const unsigned short* __restrict__ po,
    const float* __restrict__ pl, const float* __restrict__ gamma_p,
    float* __restrict__ out)
{
  const long tid = (long)blockIdx.x*256 + threadIdx.x;   // 262144
  const long bn = tid >> 3;
  const int c0 = (int)(tid & 7)*8;

  float l = 0.f;
  float o[8];
  #pragma unroll
  for (int i = 0; i < 8; ++i) o[i] = 0.f;
  #pragma unroll
  for (int s = 0; s < 8; ++s) {
    l += pl[(long)s*32768 + bn];
    uint4 v = *(const uint4*)(po + ((long)s*32768 + bn)*64 + c0);
    const unsigned short* pv = (const unsigned short*)&v;
    #pragma unroll
    for (int i = 0; i < 8; ++i)
      o[i] += __uint_as_float((unsigned int)pv[i] << 16);
  }
  const float scale = gamma_p[0] / l;
  const float* xp = x + bn*64 + c0;
  float4 x0 = *(const float4*)xp;
  float4 x1 = *(const float4*)(xp + 4);
  float4 r0, r1;
  r0.x = fmaf(scale, o[0], x0.x);
  r0.y = fmaf(scale, o[1], x0.y);
  r0.z = fmaf(scale, o[2], x0.z);
  r0.w = fmaf(scale, o[3], x0.w);
  r1.x = fmaf(scale, o[4], x1.x);
  r1.y = fmaf(scale, o[5], x1.y);
  r1.z = fmaf(scale, o[6], x1.z);
  r1.w = fmaf(scale, o[7], x1.w);
  float* op = out + bn*64 + c0;
  *(float4*)op = r0;
  *(float4*)(op + 4) = r1;
}

extern "C" void kernel_launch(void* const* d_in, const int* in_sizes, int n_in,
                              void* d_out, int out_size, void* d_ws, size_t ws_size,
                              hipStream_t stream) {
  const float* x  = (const float*)d_in[0];
  const float* kf = (const float*)d_in[1];
  const float* kg = (const float*)d_in[2];
  const float* kh = (const float*)d_in[3];
  const float* gamma = (const float*)d_in[4];
  float* out = (float*)d_out;

  char* ws = (char*)d_ws;
  unsigned short* h_p = (unsigned short*)ws;                  // 8*32*8704*2 = 4,456,448
  unsigned short* f_b = (unsigned short*)(ws + 4456448);      // 524,288
  unsigned short* g_b = (unsigned short*)(ws + 4980736);      // 524,288
  unsigned short* po  = (unsigned short*)(ws + 5505024);      // 8*8*4096*64*2 = 33,554,432
  float*          pl  = (float*)(ws + 39059456);              // 8*8*4096*4 = 1,048,576

  proj_kernel<<<512, 256, 0, stream>>>(x, kf, kg, kh, f_b, g_b, h_p);
  attn_kernel<<<dim3(16, 8, 8), 256, 0, stream>>>(f_b, g_b, h_p, po, pl);
  combine_kernel<<<1024, 256, 0, stream>>>(x, po, pl, gamma, out);
}

// Round 11
// 103.767 us; speedup vs baseline: 2.9339x; 2.4309x over previous
//
#include <hip/hip_runtime.h>
#include <hip/hip_bf16.h>

typedef __attribute__((ext_vector_type(4)))  float f32x4;
typedef __attribute__((ext_vector_type(16))) float f32x16;
typedef __attribute__((ext_vector_type(8)))  short bf16x8;

#define LOG2E 1.44269504088896340736f

// native v_exp_f32 (1 instr, ~1 ulp); plain exp2f lowers to precise OCML (~30 cyc).
#if __has_builtin(__builtin_amdgcn_exp2f)
static __device__ __forceinline__ float exp2_native(float x) {
  return __builtin_amdgcn_exp2f(x);
}
#else
extern "C" __device__ float __ocml_native_exp2_f32(float);
static __device__ __forceinline__ float exp2_native(float x) {
  return __ocml_native_exp2_f32(x);
}
#endif

// bf16 truncation pack: low ushort <- a, high ushort <- b (1x v_perm_b32).
static __device__ __forceinline__ unsigned int pack_trunc_f(float a, float b) {
  return __builtin_amdgcn_perm(__float_as_uint(b), __float_as_uint(a), 0x07060302);
}

// async global->LDS, 16B/lane: LDS dest = wave-uniform base + lane*16 (HW adds)
typedef const __attribute__((address_space(1))) unsigned int gu32;
typedef __attribute__((address_space(3))) unsigned int lu32;
static __device__ __forceinline__ void gload_lds16(const void* g, void* l) {
  __builtin_amdgcn_global_load_lds((gu32*)g, (lu32*)l, 16, 0, 0);
}

// ---------------------------------------------------------------------------
// proj: y = x(32768x64) * K^T(64x80) via MFMA 16x16x32. Block=256thr/4 waves.
// g pre-scaled by log2(e) so attn uses native exp2.
// h stored per 128-key tile as [b][kt(32)][c(64)][136 slots] bf16 (8-slot row
// pad; stride 136 gave 0 measured conflicts R4-R10), tile stride 17408 B.
// Key position within tile = bitswap2<->3(key&127): attn's S^T C-layout ==
// PV A-layout with contiguous B-frags.
// ---------------------------------------------------------------------------
__global__ __launch_bounds__(256) void proj_kernel(
    const float* __restrict__ x, const float* __restrict__ kf,
    const float* __restrict__ kg, const float* __restrict__ kh,
    unsigned short* __restrict__ f_b, unsigned short* __restrict__ g_b,
    unsigned short* __restrict__ h_p)
{
  __shared__ unsigned short Kt[80*72];
  const int t = threadIdx.x, blk = blockIdx.x;

  #pragma unroll
  for (int r = 0; r < 20; ++r) {
    int idx = r*256 + t;                 // 5120 = 80x64
    int o = idx >> 6, c = idx & 63;
    float v = (o < 8) ? kf[c*8 + o]
            : (o < 16) ? kg[c*8 + (o-8)] * LOG2E
            : kh[c*64 + (o-16)];
    Kt[o*72 + c] = (unsigned short)(__float_as_uint(v) >> 16);
  }
  __syncthreads();

  const int w = t >> 6, lane = t & 63, l15 = lane & 15, quad = lane >> 4;
  const int Rbase = blk*64 + w*16;
  const int R = Rbase + l15;

  bf16x8 af[2];
  #pragma unroll
  for (int kk = 0; kk < 2; ++kk) {
    const float* xp = x + (long)R*64 + kk*32 + quad*8;
    float4 v0 = *(const float4*)xp;
    float4 v1 = *(const float4*)(xp + 4);
    union { unsigned int u[4]; bf16x8 v; } p;
    p.u[0] = pack_trunc_f(v0.x, v0.y);
    p.u[1] = pack_trunc_f(v0.z, v0.w);
    p.u[2] = pack_trunc_f(v1.x, v1.y);
    p.u[3] = pack_trunc_f(v1.z, v1.w);
    af[kk] = p.v;
  }

  f32x4 acc[5];
  #pragma unroll
  for (int nt = 0; nt < 5; ++nt) { f32x4 z = {}; acc[nt] = z; }

  #pragma unroll
  for (int nt = 0; nt < 5; ++nt)
    #pragma unroll
    for (int kk = 0; kk < 2; ++kk) {
      bf16x8 bfv = *(const bf16x8*)&Kt[(nt*16 + l15)*72 + kk*32 + quad*8];
      acc[nt] = __builtin_amdgcn_mfma_f32_16x16x32_bf16(af[kk], bfv, acc[nt], 0, 0, 0);
    }

  const int bt = Rbase >> 12;            // batch
  const int kt = (Rbase >> 7) & 31;      // 128-key tile index
  const int base = ((blk & 1) << 6) + (w << 4);   // key&127 base for C rows
  // permuted store position: swap bits 2<->3 of (base + 4*quad + rr)
  const int pi = base + ((quad & 1) << 3) + (((quad >> 1) & 1) << 2);

  #pragma unroll
  for (int rr = 0; rr < 4; ++rr) {
    const int nq = (Rbase + quad*4 + rr) & 4095;
    unsigned short v = (unsigned short)(__float_as_uint(acc[0][rr]) >> 16);
    if (l15 < 8) f_b[((long)bt*4096 + nq)*8 + l15] = v;
    else         g_b[((long)bt*4096 + nq)*8 + (l15 - 8)] = v;
  }
  #pragma unroll
  for (int nt = 1; nt < 5; ++nt) {
    const int c = (nt - 1)*16 + l15;
    uint2 v;
    v.x = pack_trunc_f(acc[nt][0], acc[nt][1]);
    v.y = pack_trunc_f(acc[nt][2], acc[nt][3]);
    *(uint2*)(h_p + ((long)(bt*32 + kt)*64 + c)*136 + pi) = v;
  }
}

// ---------------------------------------------------------------------------
// attn: split-K flash attention (no-max softmax; |s| << 1 by construction).
// Grid (32 qtiles, 8 batch, 4 splits) = 1024 blocks = exactly 4 blocks/CU;
// block = 256 thr = 4 waves; WAVE = 32 QUERIES (R10 register law: 64 q/wave
// needs ~148 unified regs incl. AGPR acc -> spills whenever cap < 150; 32 q
// needs ~84 -> safe under the 128-reg cap of 4 waves/EU. R5 measured VGPR 52
// arch for this inner loop, never spilled).
// 128-key double-buffered tiles ([h 17408][f 2048] = 19456 B/buf, x2/block;
// 4 blocks/CU -> LDS 155648/163840). 16 waves/CU = 4 waves/EU, and each
// block contributes ONE wave per SIMD -> 4 INDEPENDENT barrier-streams per
// SIMD (R6 had 2) to overlap each other's phase stalls.
// ONE barrier per tile: barrier (drains tile-t loads) -> issue t+1 into the
// other buffer -> compute t.
// ---------------------------------------------------------------------------
__global__ __launch_bounds__(256, 4) void attn_kernel(
    const unsigned short* __restrict__ f_b, const unsigned short* __restrict__ g_b,
    const unsigned short* __restrict__ h_p, unsigned short* __restrict__ po,
    float* __restrict__ pl)
{
  __shared__ char bufs[2][19456];   // [h 17408][f 2048]

  const int t = threadIdx.x;
  const int w = t >> 6, lane = t & 63, l31 = lane & 31, a = lane >> 5;
  const int qb = blockIdx.x, b = blockIdx.y, sp = blockIdx.z;
  const int q0w = qb*128 + w*32;    // this wave's 32 queries

  // g B-frag: n = q = l31, k = a*8+j ; real channels only at lane-half a=0
  bf16x8 gf;
  {
    bf16x8 gv = *(const bf16x8*)(g_b + ((long)b*4096 + q0w + l31)*8);
    bf16x8 z = {};
    gf = (a == 0) ? gv : z;
  }

  f32x16 oacc[2];
  { f32x16 z = {}; oacc[0] = z; oacc[1] = z; }
  float l_run = 0.f;

  const char* hp_b = (const char*)h_p + (long)b*32*17408;
  const char* fb_b = (const char*)f_b + (long)b*65536;

  // stage 128-key tile kt into bufs[bi]: 19 x 1024B wave-uniform rounds,
  // round r = 4i + w (waves 0-2: 5 rounds, wave 3: 4). r<17 -> h, else f.
  // (mapping correctness-verified in R9)
  auto stage = [&](int bi, int kt) {
    const char* hsrc = hp_b + (long)kt*17408;
    const char* fsrc = fb_b + (long)kt*2048;
    char* dst = &bufs[bi][0];
    #pragma unroll
    for (int i = 0; i < 4; ++i) {
      const int r = 4*i + w;                       // 0..15: always h
      gload_lds16(hsrc + r*1024 + lane*16, dst + r*1024);
    }
    if (w == 0)      gload_lds16(hsrc + 16*1024 + lane*16, dst + 16*1024);
    else if (w < 3)  gload_lds16(fsrc + (w-1)*1024 + lane*16, dst + (16+w)*1024);
  };

  stage(0, sp*8);

  for (int ktl = 0; ktl < 8; ++ktl) {
    __syncthreads();                   // drains tile-ktl loads; protects reuse
    if (ktl < 7) stage((ktl + 1) & 1, sp*8 + ktl + 1);

    const unsigned short* hts = (const unsigned short*)&bufs[ktl & 1][0];
    const unsigned short* fts = (const unsigned short*)&bufs[ktl & 1][17408];

    #pragma unroll
    for (int mt = 0; mt < 4; ++mt) {
      // S^T sub-tile: 32 keys (storage order) x 32 queries
      bf16x8 afv = *(const bf16x8*)&fts[(mt*32 + l31)*8];
      f32x16 zz = {};
      f32x16 sc = __builtin_amdgcn_mfma_f32_32x32x16_bf16(afv, gf, zz, 0, 0, 0);

      // exp + row-sum + IMMEDIATE pack: sc dead before any PV MFMA
      unsigned int ap[2][4];           // [half][slot]
      float la = 0.f, lb = 0.f;
      #pragma unroll
      for (int r = 0; r < 16; r += 2) {
        sc[r]   = exp2_native(sc[r]);
        sc[r+1] = exp2_native(sc[r+1]);
        la += sc[r]; lb += sc[r+1];
        ap[r >> 3][(r & 7) >> 1] = pack_trunc_f(sc[r], sc[r+1]);
      }
      l_run += la + lb;

      #pragma unroll
      for (int half = 0; half < 2; ++half) {
        const int s = mt*2 + half;     // PV K-step: contraction k in [16s,16s+16)
        bf16x8 bh0 = *(const bf16x8*)&hts[(l31)*136      + s*16 + a*8];
        bf16x8 bh1 = *(const bf16x8*)&hts[(32 + l31)*136 + s*16 + a*8];
        bf16x8 av = *(const bf16x8*)&ap[half][0];
        oacc[0] = __builtin_amdgcn_mfma_f32_32x32x16_bf16(av, bh0, oacc[0], 0, 0, 0);
        oacc[1] = __builtin_amdgcn_mfma_f32_32x32x16_bf16(av, bh1, oacc[1], 0, 0, 0);
      }
    }
  }

  // partial l: lane covers 64 keys/tile for query l31; other half has rest
  l_run += __shfl_xor(l_run, 32);
  const long sb = (long)sp*8 + b;
  if (lane < 32) pl[(sb << 12) + q0w + l31] = l_run;

  // partial o: C-layout col = c = nt*32+l31, row q = q0w + (r&3)+8*(r>>2)+4a
  unsigned short* pob = po + ((sb << 12) + q0w)*64;
  #pragma unroll
  for (int nt = 0; nt < 2; ++nt)
    #pragma unroll
    for (int r = 0; r < 16; ++r) {
      const int q = (r & 3) + 8*(r >> 2) + 4*a;
      pob[(long)q*64 + nt*32 + l31] =
          (unsigned short)(__float_as_uint(oacc[nt][r]) >> 16);
    }
}

// ---------------------------------------------------------------------------
// combine: out = gamma * (sum_s po) / (sum_s pl) + x.  One thread = 8 channels.
// ---------------------------------------------------------------------------
__global__ __launch_bounds__(256) void combine_kernel(
    const float* __restrict__ x, const unsigned short* __restrict__ po,
    const float* __restrict__ pl, const float* __restrict__ gamma_p,
    float* __restrict__ out)
{
  const long tid = (long)blockIdx.x*256 + threadIdx.x;   // 262144
  const long bn = tid >> 3;
  const int c0 = (int)(tid & 7)*8;

  float l = 0.f;
  float o[8];
  #pragma unroll
  for (int i = 0; i < 8; ++i) o[i] = 0.f;
  #pragma unroll
  for (int s = 0; s < 4; ++s) {
    l += pl[(long)s*32768 + bn];
    uint4 v = *(const uint4*)(po + ((long)s*32768 + bn)*64 + c0);
    const unsigned short* pv = (const unsigned short*)&v;
    #pragma unroll
    for (int i = 0; i < 8; ++i)
      o[i] += __uint_as_float((unsigned int)pv[i] << 16);
  }
  const float scale = gamma_p[0] / l;
  const float* xp = x + bn*64 + c0;
  float4 x0 = *(const float4*)xp;
  float4 x1 = *(const float4*)(xp + 4);
  float4 r0, r1;
  r0.x = fmaf(scale, o[0], x0.x);
  r0.y = fmaf(scale, o[1], x0.y);
  r0.z = fmaf(scale, o[2], x0.z);
  r0.w = fmaf(scale, o[3], x0.w);
  r1.x = fmaf(scale, o[4], x1.x);
  r1.y = fmaf(scale, o[5], x1.y);
  r1.z = fmaf(scale, o[6], x1.z);
  r1.w = fmaf(scale, o[7], x1.w);
  float* op = out + bn*64 + c0;
  *(float4*)op = r0;
  *(float4*)(op + 4) = r1;
}

extern "C" void kernel_launch(void* const* d_in, const int* in_sizes, int n_in,
                              void* d_out, int out_size, void* d_ws, size_t ws_size,
                              hipStream_t stream) {
  const float* x  = (const float*)d_in[0];
  const float* kf = (const float*)d_in[1];
  const float* kg = (const float*)d_in[2];
  const float* kh = (const float*)d_in[3];
  const float* gamma = (const float*)d_in[4];
  float* out = (float*)d_out;

  char* ws = (char*)d_ws;
  unsigned short* h_p = (unsigned short*)ws;                  // 8*32*8704*2 = 4,456,448
  unsigned short* f_b = (unsigned short*)(ws + 4456448);      // 524,288
  unsigned short* g_b = (unsigned short*)(ws + 4980736);      // 524,288
  unsigned short* po  = (unsigned short*)(ws + 5505024);      // 4*8*4096*64*2 = 16,777,216
  float*          pl  = (float*)(ws + 22282240);              // 4*8*4096*4 = 524,288

  proj_kernel<<<512, 256, 0, stream>>>(x, kf, kg, kh, f_b, g_b, h_p);
  attn_kernel<<<dim3(32, 8, 4), 256, 0, stream>>>(f_b, g_b, h_p, po, pl);
  combine_kernel<<<1024, 256, 0, stream>>>(x, po, pl, gamma, out);
}